// Round 5
// baseline (688.230 us; speedup 1.0000x reference)
//
#include <hip/hip_runtime.h>
#include <hip/hip_bf16.h>

// DIM=768, H=4, D_H=192, R_H=4, N_EXP=6, TOPK=3, BETA=0.5, BATCH=65536
// Routing is batch-independent -> fold softmax/topk/renorm/BETA into per-head
// per-expert weights c[h][e], then fold c into A:
//   Ac[h][s][d] = c[h][e] * A[e][d][r],  s = e*4+r (24 slots), layout [4][24][192].
// B flat is already [24][192], used raw.
// out[b, h*192+d] = z + sum_s (sum_d' z[d']*Ac[h][s][d']) * B[s][d]
//
// v5 "lane = row": each lane owns one (row, head) segment's FULL dot products.
// Table addresses depend only on blockIdx + loop counters -> wave-uniform ->
// compiler emits scalar s_load (SMEM pipe, SGPR operand in v_fma). This kills
// round-3's wall (LDS at 78 TB/s peak broadcasting 8x-replicated data) and
// rounds-2/4's wall (allocator clamps 256-thd kernels to 64 VGPR and spills):
// per-lane state is tmp[24] + temps ~= 50 VGPR. No LDS, no shuffles, no spill.
// z: per-lane strided f4 loads; unroll-4 consumes each 64B line fully via L1.
// Phase 2 re-reads z (192 MiB fits 256 MiB L3). Stores merge in L2.

typedef float f4 __attribute__((ext_vector_type(4)));

__global__ void dff_setup(const float* __restrict__ A,
                          const float* __restrict__ Zs,
                          const float* __restrict__ Za,
                          float* __restrict__ Ac) {
  __shared__ float c[4][6];
  const int t = threadIdx.x;
  if (t < 4) {
    const int h = t;
    float cc[6] = {0.f, 0.f, 0.f, 0.f, 0.f, 0.f};
    for (int rt = 0; rt < 2; ++rt) {
      const float* Z = rt ? Za : Zs;
      float zz[6];
      float mx = -1e30f;
      for (int e = 0; e < 6; ++e) { zz[e] = Z[h * 6 + e]; mx = fmaxf(mx, zz[e]); }
      float p[6];
      float sum = 0.f;
      for (int e = 0; e < 6; ++e) { p[e] = expf(zz[e] - mx); sum += p[e]; }
      for (int e = 0; e < 6; ++e) p[e] /= sum;
      // top-3 (ties -> lowest index, matching lax.top_k)
      bool used[6] = {false, false, false, false, false, false};
      float ws = 0.f;
      int sel[3];
      float pv[3];
      for (int k = 0; k < 3; ++k) {
        int best = -1;
        float bv = -1.f;
        for (int e = 0; e < 6; ++e)
          if (!used[e] && p[e] > bv) { bv = p[e]; best = e; }
        used[best] = true;
        sel[k] = best;
        pv[k] = bv;
        ws += bv;
      }
      const float inv = 1.f / (ws + 1e-8f);
      for (int k = 0; k < 3; ++k) cc[sel[k]] += pv[k] * inv;
    }
    for (int e = 0; e < 6; ++e) c[h][e] = 0.5f * cc[e];  // BETA folded in
  }
  __syncthreads();
  // Ac[h][s][d] = c[h][e] * A[e][d][r];  A flat: A[e*768 + d*4 + r]
  for (int idx = threadIdx.x; idx < 4 * 24 * 192; idx += blockDim.x) {
    const int h = idx / (24 * 192);
    const int rem = idx % (24 * 192);
    const int s = rem / 192;
    const int d = rem % 192;
    const int e = s >> 2, r = s & 3;
    Ac[idx] = c[h][e] * A[e * 768 + d * 4 + r];
  }
}

__global__ __launch_bounds__(256)
void dff_main(const float* __restrict__ z,
              const float* __restrict__ B,
              const float* __restrict__ Ac,
              float* __restrict__ out) {
  const int t = threadIdx.x;                 // 0..255
  const int bi = blockIdx.x;                 // 0..1023
  const int h = bi & 3;                      // head, block-uniform
  const int row = (bi >> 2) * 256 + t;       // 256 blocks/head * 256 rows
  const float* __restrict__ zp = z + (size_t)row * 768 + h * 192;
  float* __restrict__ op = out + (size_t)row * 768 + h * 192;
  const float* __restrict__ Ah = Ac + h * (24 * 192);  // uniform

  float tmp[24];
#pragma unroll
  for (int s = 0; s < 24; ++s) tmp[s] = 0.f;

  // phase 1: tmp[s] = sum_d z[d] * Ac[h][s][d].  Table address is
  // wave-uniform (s_load -> SGPR); z is per-lane f4 (unroll 4 = one 64B line).
#pragma unroll 4
  for (int j = 0; j < 48; ++j) {
    const f4 zv = reinterpret_cast<const f4*>(zp)[j];
    const float* __restrict__ aj = Ah + 4 * j;
#pragma unroll
    for (int s = 0; s < 24; ++s) {
      const f4 a = *reinterpret_cast<const f4*>(aj + s * 192);
      tmp[s] = fmaf(zv.x, a.x,
               fmaf(zv.y, a.y,
               fmaf(zv.z, a.z,
               fmaf(zv.w, a.w, tmp[s]))));
    }
  }

  // phase 2: out[d] = z[d] + sum_s tmp[s] * B[s][d].  B read raw (weights
  // already folded into tmp via Ac). z re-read served by L1/L3.
#pragma unroll 2
  for (int j = 0; j < 48; ++j) {
    f4 o = reinterpret_cast<const f4*>(zp)[j];
    const float* __restrict__ bj = B + 4 * j;
#pragma unroll
    for (int s = 0; s < 24; ++s) {
      const f4 b = *reinterpret_cast<const f4*>(bj + s * 192);
      const float tv = tmp[s];
      o.x = fmaf(tv, b.x, o.x);
      o.y = fmaf(tv, b.y, o.y);
      o.z = fmaf(tv, b.z, o.z);
      o.w = fmaf(tv, b.w, o.w);
    }
    __builtin_nontemporal_store(o, reinterpret_cast<f4*>(op) + j);
  }
}

extern "C" void kernel_launch(void* const* d_in, const int* in_sizes, int n_in,
                              void* d_out, int out_size, void* d_ws, size_t ws_size,
                              hipStream_t stream) {
  const float* z  = (const float*)d_in[0];   // [65536, 768]
  const float* A  = (const float*)d_in[1];   // [6, 192, 4]
  const float* B  = (const float*)d_in[2];   // [6, 4, 192] == [24][192]
  const float* Zs = (const float*)d_in[3];   // [4, 6]
  const float* Za = (const float*)d_in[4];   // [4, 6]
  float* out = (float*)d_out;                // [65536, 768]
  float* Ac = (float*)d_ws;                  // 4*24*192 floats = 73728 B

  dff_setup<<<1, 256, 0, stream>>>(A, Zs, Za, Ac);
  dff_main<<<1024, 256, 0, stream>>>(z, B, Ac, out);
}

// Round 6
// 191.314 us; speedup vs baseline: 3.5974x; 3.5974x over previous
//
#include <hip/hip_runtime.h>
#include <hip/hip_bf16.h>

// DIM=768, H=4, D_H=192, R_H=4, N_EXP=6, TOPK=3, BETA=0.5, BATCH=65536
// Routing is batch-independent. Fold softmax/topk/renorm/BETA into c[h][e],
// then precompute the DENSE per-head matrix, stored transposed in bf16:
//   Wt[h][n][k] = sum_s c[h][s/4] * A[s/4][k][s%4] * B[s/4][s%4][n]
// (295 KB total -> L2-resident). Main op: out = z + z @ W[h] per head ->
// bf16 MFMA GEMM, M=65536, K=N=192. Compute ~10us at MFMA rate; HBM 384 MB
// -> ~61us floor. Residual folded into acc init (no epilogue z re-read).
//
// Structure constraints learned r1-r5: 1 wave/block (allocator honors >64
// VGPR only for 64-thread blocks), no LDS (r3 was LDS-return-BW bound),
// fully coalesced wave-level access (r5's per-lane stride was fatal).
// mfma_f32_16x16x32_bf16 layouts (cdna4_isa / m89-verified):
//   A: row=l&15, k=(l>>4)*8+j   B: col=l&15, same k   C/D: col=l&15, row=(l>>4)*4+r

typedef short bf16x8 __attribute__((ext_vector_type(8)));
typedef float f32x4 __attribute__((ext_vector_type(4)));
typedef unsigned int u32;

__global__ void dff_setup(const float* __restrict__ A,
                          const float* __restrict__ Bm,
                          const float* __restrict__ Zs,
                          const float* __restrict__ Za,
                          __hip_bfloat16* __restrict__ Wt) {
  __shared__ float c[4][6];
  const int t = threadIdx.x;
  if (t < 4) {
    const int h = t;
    float cc[6] = {0.f, 0.f, 0.f, 0.f, 0.f, 0.f};
    for (int rt = 0; rt < 2; ++rt) {
      const float* Z = rt ? Za : Zs;
      float zz[6];
      float mx = -1e30f;
      for (int e = 0; e < 6; ++e) { zz[e] = Z[h * 6 + e]; mx = fmaxf(mx, zz[e]); }
      float p[6];
      float sum = 0.f;
      for (int e = 0; e < 6; ++e) { p[e] = expf(zz[e] - mx); sum += p[e]; }
      for (int e = 0; e < 6; ++e) p[e] /= sum;
      // top-3 (ties -> lowest index, matching lax.top_k)
      bool used[6] = {false, false, false, false, false, false};
      float ws = 0.f;
      int sel[3];
      float pv[3];
      for (int k = 0; k < 3; ++k) {
        int best = -1;
        float bv = -1.f;
        for (int e = 0; e < 6; ++e)
          if (!used[e] && p[e] > bv) { bv = p[e]; best = e; }
        used[best] = true;
        sel[k] = best;
        pv[k] = bv;
        ws += bv;
      }
      const float inv = 1.f / (ws + 1e-8f);
      for (int k = 0; k < 3; ++k) cc[sel[k]] += pv[k] * inv;
    }
    for (int e = 0; e < 6; ++e) c[h][e] = 0.5f * cc[e];  // BETA folded in
  }
  __syncthreads();
  // Wt[h][n][k] = sum_s c[h][e]*A[e*768 + k*4 + r]*Bm[s*192 + n],  s=e*4+r
  for (int idx = blockIdx.x * blockDim.x + threadIdx.x; idx < 4 * 192 * 192;
       idx += gridDim.x * blockDim.x) {
    const int h = idx / (192 * 192);
    const int rem = idx % (192 * 192);
    const int n = rem / 192;
    const int k = rem % 192;
    float acc = 0.f;
#pragma unroll
    for (int s = 0; s < 24; ++s) {
      const int e = s >> 2, r = s & 3;
      acc += c[h][e] * A[e * 768 + k * 4 + r] * Bm[s * 192 + n];
    }
    Wt[idx] = __float2bfloat16(acc);
  }
}

// f32 -> bf16 (round half up via +0x8000) packed pair into one u32.
__device__ __forceinline__ u32 pack_bf16(float a, float b) {
  const u32 ua = __builtin_bit_cast(u32, a) + 0x8000u;
  const u32 ub = __builtin_bit_cast(u32, b) + 0x8000u;
  return (ua >> 16) | (ub & 0xFFFF0000u);
}

__global__ __launch_bounds__(64, 2)
void dff_mfma(const float* __restrict__ z,
              const __hip_bfloat16* __restrict__ Wt,
              float* __restrict__ out) {
  const int l = threadIdx.x;        // 0..63
  const int lr = l & 15;
  const int lg = l >> 4;            // 0..3
  const int h = blockIdx.y;         // head
  const size_t row0 = (size_t)blockIdx.x * 16;   // 4096 tiles
  const float* __restrict__ zb = z + row0 * 768 + h * 192;
  float* __restrict__ ob = out + row0 * 768 + h * 192;
  const short* __restrict__ Wh =
      reinterpret_cast<const short*>(Wt) + h * (192 * 192);

  // acc init = residual z at C/D positions: row=lg*4+r, col=nt*16+lr
  f32x4 acc[12];
#pragma unroll
  for (int nt = 0; nt < 12; ++nt)
#pragma unroll
    for (int r = 0; r < 4; ++r)
      acc[nt][r] = zb[(size_t)(lg * 4 + r) * 768 + nt * 16 + lr];

#pragma unroll
  for (int kb = 0; kb < 6; ++kb) {
    // A fragment: z[row0+lr][kb*32 + lg*8 + j], j=0..7 (f32 -> bf16 pack).
    // Wave footprint: 16 rows x 128B contiguous — fully coalesced.
    const float* ap = zb + (size_t)lr * 768 + kb * 32 + lg * 8;
    const f32x4 a0 = *reinterpret_cast<const f32x4*>(ap);
    const f32x4 a1 = *reinterpret_cast<const f32x4*>(ap + 4);
    u32 ap32[4];
    ap32[0] = pack_bf16(a0.x, a0.y);
    ap32[1] = pack_bf16(a0.z, a0.w);
    ap32[2] = pack_bf16(a1.x, a1.y);
    ap32[3] = pack_bf16(a1.z, a1.w);
    const bf16x8 af = __builtin_bit_cast(bf16x8, ap32);

#pragma unroll
    for (int nt = 0; nt < 12; ++nt) {
      // B fragment: Wt[h][nt*16+lr][kb*32 + lg*8 + j] — one 16B load.
      const bf16x8 bf = *reinterpret_cast<const bf16x8*>(
          Wh + (size_t)(nt * 16 + lr) * 192 + kb * 32 + lg * 8);
      acc[nt] = __builtin_amdgcn_mfma_f32_16x16x32_bf16(af, bf, acc[nt], 0, 0, 0);
    }
  }

  // store: out[row0+lg*4+r][h*192 + nt*16 + lr]; 16 lanes = 64B contiguous.
#pragma unroll
  for (int nt = 0; nt < 12; ++nt)
#pragma unroll
    for (int r = 0; r < 4; ++r)
      __builtin_nontemporal_store(acc[nt][r],
                                  &ob[(size_t)(lg * 4 + r) * 768 + nt * 16 + lr]);
}

extern "C" void kernel_launch(void* const* d_in, const int* in_sizes, int n_in,
                              void* d_out, int out_size, void* d_ws, size_t ws_size,
                              hipStream_t stream) {
  const float* z  = (const float*)d_in[0];   // [65536, 768]
  const float* A  = (const float*)d_in[1];   // [6, 192, 4]
  const float* Bm = (const float*)d_in[2];   // [6, 4, 192] == [24][192]
  const float* Zs = (const float*)d_in[3];   // [4, 6]
  const float* Za = (const float*)d_in[4];   // [4, 6]
  float* out = (float*)d_out;                // [65536, 768]
  __hip_bfloat16* Wt = (__hip_bfloat16*)d_ws; // [4][192][192] bf16 = 294,912 B

  dff_setup<<<192, 256, 0, stream>>>(A, Bm, Zs, Za, Wt);
  dff_mfma<<<dim3(4096, 4), 64, 0, stream>>>(z, Wt, out);
}

// Round 7
// 168.169 us; speedup vs baseline: 4.0925x; 1.1376x over previous
//
#include <hip/hip_runtime.h>
#include <hip/hip_bf16.h>

// DIM=768, H=4, D_H=192, R_H=4, N_EXP=6, TOPK=3, BETA=0.5, BATCH=65536
// Routing is batch-independent. Fold softmax/topk/renorm/BETA into c[h][e],
// then precompute the DENSE per-head matrix, stored transposed in bf16:
//   Wt[h][n][k] = sum_s c[h][s/4] * A[s/4][k][s%4] * B[s/4][s%4][n]
// (295 KB total -> L2-resident). Main op: out = z + z @ W[h] per head.
//
// v7: TRANSPOSED MFMA — compute T = W^T * z^T (A-operand = Wt[n][k] directly,
// B-operand = z^T). D-fragment then holds 4 CONSECUTIVE n per lane ->
// residual-init and store are f32x4 (r6's scalar-dword scatter was the
// latency wall: MfmaUtil 2.9%, all pipes idle). 32 rows/wave (2 batch-tiles
// share each Wt fragment); two nt-halves keep live acc at 48 VGPR so total
// stays ~85-100 (r1/r4 lesson: demand must stay inside what the allocator
// honors). z-init warms L1 (24KB/wave); B-frag re-reads are L1 hits.
// mfma_f32_16x16x32_bf16 layouts (m89-verified):
//   A: row=l&15, k=(l>>4)*8+j   B: col=l&15, same k   C/D: col=l&15, row=(l>>4)*4+r

typedef short bf16x8 __attribute__((ext_vector_type(8)));
typedef float f32x4 __attribute__((ext_vector_type(4)));
typedef unsigned int u32;

__global__ void dff_setup(const float* __restrict__ A,
                          const float* __restrict__ Bm,
                          const float* __restrict__ Zs,
                          const float* __restrict__ Za,
                          __hip_bfloat16* __restrict__ Wt) {
  __shared__ float c[4][6];
  const int t = threadIdx.x;
  if (t < 4) {
    const int h = t;
    float cc[6] = {0.f, 0.f, 0.f, 0.f, 0.f, 0.f};
    for (int rt = 0; rt < 2; ++rt) {
      const float* Z = rt ? Za : Zs;
      float zz[6];
      float mx = -1e30f;
      for (int e = 0; e < 6; ++e) { zz[e] = Z[h * 6 + e]; mx = fmaxf(mx, zz[e]); }
      float p[6];
      float sum = 0.f;
      for (int e = 0; e < 6; ++e) { p[e] = expf(zz[e] - mx); sum += p[e]; }
      for (int e = 0; e < 6; ++e) p[e] /= sum;
      // top-3 (ties -> lowest index, matching lax.top_k)
      bool used[6] = {false, false, false, false, false, false};
      float ws = 0.f;
      int sel[3];
      float pv[3];
      for (int k = 0; k < 3; ++k) {
        int best = -1;
        float bv = -1.f;
        for (int e = 0; e < 6; ++e)
          if (!used[e] && p[e] > bv) { bv = p[e]; best = e; }
        used[best] = true;
        sel[k] = best;
        pv[k] = bv;
        ws += bv;
      }
      const float inv = 1.f / (ws + 1e-8f);
      for (int k = 0; k < 3; ++k) cc[sel[k]] += pv[k] * inv;
    }
    for (int e = 0; e < 6; ++e) c[h][e] = 0.5f * cc[e];  // BETA folded in
  }
  __syncthreads();
  // Wt[h][n][k] = sum_s c[h][e]*A[e*768 + k*4 + r]*Bm[s*192 + n],  s=e*4+r
  for (int idx = blockIdx.x * blockDim.x + threadIdx.x; idx < 4 * 192 * 192;
       idx += gridDim.x * blockDim.x) {
    const int h = idx / (192 * 192);
    const int rem = idx % (192 * 192);
    const int n = rem / 192;
    const int k = rem % 192;
    float acc = 0.f;
#pragma unroll
    for (int s = 0; s < 24; ++s) {
      const int e = s >> 2, r = s & 3;
      acc += c[h][e] * A[e * 768 + k * 4 + r] * Bm[s * 192 + n];
    }
    Wt[idx] = __float2bfloat16(acc);
  }
}

// f32 -> bf16 (round half up via +0x8000) packed pair into one u32.
__device__ __forceinline__ u32 pack_bf16(float a, float b) {
  const u32 ua = __builtin_bit_cast(u32, a) + 0x8000u;
  const u32 ub = __builtin_bit_cast(u32, b) + 0x8000u;
  return (ua >> 16) | (ub & 0xFFFF0000u);
}

__global__ __launch_bounds__(64, 2)
void dff_mfma(const float* __restrict__ z,
              const __hip_bfloat16* __restrict__ Wt,
              float* __restrict__ out) {
  const int l = threadIdx.x;        // 0..63
  const int lr = l & 15;
  const int lg = l >> 4;            // 0..3
  const int h = blockIdx.y;         // head
  const size_t row0 = (size_t)blockIdx.x * 32;   // 2048 blocks
  const float* __restrict__ zb = z + row0 * 768 + h * 192;
  float* __restrict__ ob = out + row0 * 768 + h * 192;
  const short* __restrict__ Wh =
      reinterpret_cast<const short*>(Wt) + h * (192 * 192);

  // Two halves of the n-range (6 tiles each) to bound live registers.
#pragma unroll 1
  for (int nh = 0; nh < 2; ++nh) {
    const int n0 = nh * 96;  // 6 tiles * 16

    // acc[bt][i]: D tile (n-tile n0/16+i, batch-tile bt). Residual init:
    // f32x4 at out-position — rows bt*16+lr, cols n0 + i*16 + lg*4 .. +3.
    f32x4 acc[2][6];
#pragma unroll
    for (int bt = 0; bt < 2; ++bt)
#pragma unroll
      for (int i = 0; i < 6; ++i)
        acc[bt][i] = *reinterpret_cast<const f32x4*>(
            zb + (size_t)(bt * 16 + lr) * 768 + n0 + i * 16 + lg * 4);

#pragma unroll 1
    for (int kb = 0; kb < 6; ++kb) {
      // B fragments (z^T): col = batch row lr, k = kb*32 + lg*8 + j.
      // 16 rows x 128B contiguous per bt — coalesced, L1-hot after init.
      bf16x8 bfrag[2];
#pragma unroll
      for (int bt = 0; bt < 2; ++bt) {
        const float* p = zb + (size_t)(bt * 16 + lr) * 768 + kb * 32 + lg * 8;
        const f32x4 x0 = *reinterpret_cast<const f32x4*>(p);
        const f32x4 x1 = *reinterpret_cast<const f32x4*>(p + 4);
        u32 w[4];
        w[0] = pack_bf16(x0.x, x0.y);
        w[1] = pack_bf16(x0.z, x0.w);
        w[2] = pack_bf16(x1.x, x1.y);
        w[3] = pack_bf16(x1.z, x1.w);
        bfrag[bt] = __builtin_bit_cast(bf16x8, w);
      }
      // A fragments (Wt): row = n = n0+i*16+lr, k as above. One 16B L2 load
      // feeds TWO MFMAs (both batch-tiles).
#pragma unroll
      for (int i = 0; i < 6; ++i) {
        const bf16x8 afrag = *reinterpret_cast<const bf16x8*>(
            Wh + (size_t)(n0 + i * 16 + lr) * 192 + kb * 32 + lg * 8);
        acc[0][i] = __builtin_amdgcn_mfma_f32_16x16x32_bf16(afrag, bfrag[0],
                                                            acc[0][i], 0, 0, 0);
        acc[1][i] = __builtin_amdgcn_mfma_f32_16x16x32_bf16(afrag, bfrag[1],
                                                            acc[1][i], 0, 0, 0);
      }
    }

    // store: f32x4, rows bt*16+lr, cols n0+i*16+lg*4 — 1KB/wave-instruction.
#pragma unroll
    for (int bt = 0; bt < 2; ++bt)
#pragma unroll
      for (int i = 0; i < 6; ++i)
        __builtin_nontemporal_store(
            acc[bt][i],
            reinterpret_cast<f32x4*>(ob + (size_t)(bt * 16 + lr) * 768 + n0 +
                                     i * 16 + lg * 4));
  }
}

extern "C" void kernel_launch(void* const* d_in, const int* in_sizes, int n_in,
                              void* d_out, int out_size, void* d_ws, size_t ws_size,
                              hipStream_t stream) {
  const float* z  = (const float*)d_in[0];   // [65536, 768]
  const float* A  = (const float*)d_in[1];   // [6, 192, 4]
  const float* Bm = (const float*)d_in[2];   // [6, 4, 192] == [24][192]
  const float* Zs = (const float*)d_in[3];   // [4, 6]
  const float* Za = (const float*)d_in[4];   // [4, 6]
  float* out = (float*)d_out;                // [65536, 768]
  __hip_bfloat16* Wt = (__hip_bfloat16*)d_ws; // [4][192][192] bf16 = 294,912 B

  dff_setup<<<192, 256, 0, stream>>>(A, Bm, Zs, Za, Wt);
  dff_mfma<<<dim3(2048, 4), 64, 0, stream>>>(z, Wt, out);
}